// Round 2
// baseline (2079.211 us; speedup 1.0000x reference)
//
#include <hip/hip_runtime.h>
#include <hip/hip_bf16.h>
#include <stdint.h>

typedef __hip_bfloat16 bf16;
typedef __attribute__((ext_vector_type(8))) short bf16x8;
typedef __attribute__((ext_vector_type(4))) float f32x4;

#define DEV static __device__ __forceinline__

DEV float b2f(bf16 v) { return __bfloat162float(v); }
DEV bf16  f2b(float v) { return __float2bfloat16(v); }

DEV void gload16(const void* g, void* l) {
  __builtin_amdgcn_global_load_lds(
      (__attribute__((address_space(1))) void*)(void*)g,
      (__attribute__((address_space(3))) void*)l, 16, 0, 0);
}

DEV f32x4 mfma16(bf16x8 a, bf16x8 b, f32x4 c) {
  return __builtin_amdgcn_mfma_f32_16x16x32_bf16(a, b, c, 0, 0, 0);
}

// ---------------- embed: x = emb[tok]*32 + pe (all f32) ----------------
__global__ __launch_bounds__(256) void embed_kernel(
    const int* __restrict__ tok, const float* __restrict__ emb,
    const float* __restrict__ pe, float* __restrict__ x)
{
  const int r = blockIdx.x, t = threadIdx.x;
  const int s = r & 1023;
  const int tk = tok[r];
  const int d = t * 4;
  const float* ep = emb + (size_t)tk * 1024 + d;
  const float* pp = pe + (size_t)s * 1024 + d;
  float* xp = x + (size_t)r * 1024 + d;
  #pragma unroll
  for (int j = 0; j < 4; ++j)
    xp[j] = ep[j] * 32.0f + pp[j];
}

// ---------------- layernorm: h = LN(x)*g + b (f32 in, bf16 out) ----------------
__global__ __launch_bounds__(256) void ln_kernel(
    const float* __restrict__ x, const float* __restrict__ g,
    const float* __restrict__ be, bf16* __restrict__ h)
{
  const int r = blockIdx.x, t = threadIdx.x;
  const float4 v = ((const float4*)(x + (size_t)r * 1024))[t];
  float s  = v.x + v.y + v.z + v.w;
  float sq = v.x * v.x + v.y * v.y + v.z * v.z + v.w * v.w;
  #pragma unroll
  for (int d = 1; d < 64; d <<= 1) {
    s  += __shfl_xor(s, d);
    sq += __shfl_xor(sq, d);
  }
  __shared__ float red[8];
  const int w = t >> 6, l = t & 63;
  if (l == 0) { red[w] = s; red[4 + w] = sq; }
  __syncthreads();
  s  = red[0] + red[1] + red[2] + red[3];
  sq = red[4] + red[5] + red[6] + red[7];
  const float mean = s * (1.0f / 1024.0f);
  const float var  = sq * (1.0f / 1024.0f) - mean * mean;
  const float inv  = 1.0f / sqrtf(var + 1e-5f);
  bf16* hp = h + (size_t)r * 1024 + t * 4;
  const float* gp = g + t * 4;
  const float* bp = be + t * 4;
  const float vv[4] = {v.x, v.y, v.z, v.w};
  #pragma unroll
  for (int j = 0; j < 4; ++j)
    hp[j] = f2b((vv[j] - mean) * inv * gp[j] + bp[j]);
}

// ------------- transpose+cast: out(bf16)[c][r] = in(f32)[r][c] -------------
// grid: (C/64, R/64), block 256
__global__ __launch_bounds__(256) void transpose_cast_kernel(
    const float* __restrict__ in, bf16* __restrict__ out, int ldin, int ldout)
{
  __shared__ bf16 tile[64][64];
  const int t = threadIdx.x;
  const int r0 = blockIdx.y * 64, c0 = blockIdx.x * 64;
  #pragma unroll
  for (int i = 0; i < 4; ++i) {
    const int r = i * 16 + (t >> 4), c = (t & 15) * 4;
    const float4 v = *(const float4*)&in[(size_t)(r0 + r) * ldin + c0 + c];
    tile[r][c + 0] = f2b(v.x);
    tile[r][c + 1] = f2b(v.y);
    tile[r][c + 2] = f2b(v.z);
    tile[r][c + 3] = f2b(v.w);
  }
  __syncthreads();
  #pragma unroll
  for (int i = 0; i < 2; ++i) {
    const int oc = i * 32 + (t >> 3);
    const int rr = (t & 7) * 8;
    unsigned short tmp[8] __attribute__((aligned(16)));
    #pragma unroll
    for (int j = 0; j < 8; ++j)
      tmp[j] = ((const unsigned short*)tile)[(rr + j) * 64 + oc];
    *(uint4*)&out[(size_t)(c0 + oc) * ldout + r0 + rr] = *(const uint4*)tmp;
  }
}

// ---- v transpose (bf16->bf16): vT[bh][dk][s] = qkv[b*S+s][2048+h*64+dk] ----
// grid: (S/64, B*H), block 256
__global__ __launch_bounds__(256) void transpose_v_kernel(
    const bf16* __restrict__ qkv, bf16* __restrict__ vT)
{
  __shared__ bf16 tile[64][64];
  const int t = threadIdx.x;
  const int s0 = blockIdx.x * 64;
  const int bh = blockIdx.y;
  const int b = bh >> 4, h = bh & 15;
  const bf16* in = qkv + (size_t)(b * 1024) * 3072 + 2048 + h * 64;
  #pragma unroll
  for (int i = 0; i < 2; ++i) {
    const int r = i * 32 + (t >> 3), c = (t & 7) * 8;
    *(uint4*)&tile[r][c] = *(const uint4*)&in[(size_t)(s0 + r) * 3072 + c];
  }
  __syncthreads();
  bf16* out = vT + (size_t)(bh * 64) * 1024;
  #pragma unroll
  for (int i = 0; i < 2; ++i) {
    const int oc = i * 32 + (t >> 3);   // dk
    const int rr = (t & 7) * 8;         // s offset
    unsigned short tmp[8] __attribute__((aligned(16)));
    #pragma unroll
    for (int j = 0; j < 8; ++j)
      tmp[j] = ((const unsigned short*)tile)[(rr + j) * 64 + oc];
    *(uint4*)&out[(size_t)oc * 1024 + s0 + rr] = *(const uint4*)tmp;
  }
}

// ---------------- GEMM: C(MxN) = A(MxK,row) * BT(NxK,row)^T (+epilogue) ------
// EPI: 0 = bf16 store; 1 = +bias f32 store (logits); 2 = gelu(acc+bias) bf16;
//      3 = f32 residual: X += acc + bias
// grid: (M/128)*(N/128), block 256 (4 waves 2x2), BK=32
template<int EPI>
__global__ __launch_bounds__(256) void gemm_bt(
    const bf16* __restrict__ A, int lda,
    const bf16* __restrict__ BT, int ldb,
    void* __restrict__ Cp, int ldc,
    const float* __restrict__ bias,
    int K, int nbn)
{
  __shared__ bf16 As[128 * 32];
  __shared__ bf16 Bs[128 * 32];
  const int t = threadIdx.x;
  const int bm = blockIdx.x / nbn, bn = blockIdx.x % nbn;
  const int w = t >> 6, l = t & 63;
  const int wr = (w >> 1) * 64, wc = (w & 1) * 64;
  const int l15 = l & 15, l4 = l >> 4;

  const bf16* gA = A  + (size_t)(bm * 128 + (t >> 2)) * lda + (t & 3) * 8;
  const bf16* gB = BT + (size_t)(bn * 128 + (t >> 2)) * ldb + (t & 3) * 8;
  bf16* lA = As + w * 512;
  bf16* lB = Bs + w * 512;

  f32x4 acc[4][4];
  #pragma unroll
  for (int m = 0; m < 4; ++m)
    #pragma unroll
    for (int n = 0; n < 4; ++n)
      acc[m][n] = (f32x4){0.f, 0.f, 0.f, 0.f};

  for (int k0 = 0; k0 < K; k0 += 32) {
    gload16(gA + k0, lA);
    gload16(gA + (size_t)64 * lda + k0, lA + 2048);
    gload16(gB + k0, lB);
    gload16(gB + (size_t)64 * ldb + k0, lB + 2048);
    __syncthreads();
    bf16x8 af[4], bfr[4];
    #pragma unroll
    for (int m = 0; m < 4; ++m)
      af[m] = *(const bf16x8*)&As[(wr + m * 16 + l15) * 32 + l4 * 8];
    #pragma unroll
    for (int n = 0; n < 4; ++n)
      bfr[n] = *(const bf16x8*)&Bs[(wc + n * 16 + l15) * 32 + l4 * 8];
    #pragma unroll
    for (int m = 0; m < 4; ++m)
      #pragma unroll
      for (int n = 0; n < 4; ++n)
        acc[m][n] = mfma16(af[m], bfr[n], acc[m][n]);
    __syncthreads();
  }

  const int crow = bm * 128 + wr, ccol = bn * 128 + wc;
  #pragma unroll
  for (int n = 0; n < 4; ++n) {
    const int col = ccol + n * 16 + l15;
    float bv = 0.f;
    if (EPI != 0) bv = bias[col];
    #pragma unroll
    for (int m = 0; m < 4; ++m) {
      const int row = crow + m * 16 + l4 * 4;
      #pragma unroll
      for (int r = 0; r < 4; ++r) {
        const float v = acc[m][n][r];
        if (EPI == 0) {
          ((bf16*)Cp)[(size_t)(row + r) * ldc + col] = f2b(v);
        } else if (EPI == 1) {
          ((float*)Cp)[(size_t)(row + r) * ldc + col] = v + bv;
        } else if (EPI == 2) {
          const float u = v + bv;
          const float gel = 0.5f * u * (1.0f + erff(u * 0.70710678118654752f));
          ((bf16*)Cp)[(size_t)(row + r) * ldc + col] = f2b(gel);
        } else {
          float* X = (float*)Cp;
          X[(size_t)(row + r) * ldc + col] += v + bv;
        }
      }
    }
  }
}

// ---------------- flash attention ----------------
// grid: (S/128, B*H), block 256 (4 waves; wave w owns q-rows w*32..w*32+31)
__global__ __launch_bounds__(256) void attn_kernel(
    const bf16* __restrict__ qkv, const bf16* __restrict__ vT,
    const int* __restrict__ tokens, bf16* __restrict__ ctx)
{
  __shared__ bf16 Ks[128 * 64];
  __shared__ bf16 VTs[64 * 128];
  __shared__ bf16 Ps[128 * 128];

  const int qt = blockIdx.x;
  const int bh = blockIdx.y;
  const int b = bh >> 4, h = bh & 15;
  const int t = threadIdx.x, w = t >> 6, l = t & 63;
  const int l15 = l & 15, l4 = l >> 4;
  const int q0 = qt * 128;

  // Q fragments in registers (each wave its own 32 rows)
  bf16x8 aq[2][2];
  #pragma unroll
  for (int m = 0; m < 2; ++m)
    #pragma unroll
    for (int ks = 0; ks < 2; ++ks)
      aq[m][ks] = *(const bf16x8*)(qkv +
          (size_t)(b * 1024 + q0 + w * 32 + m * 16 + l15) * 3072 +
          h * 64 + ks * 32 + l4 * 8);

  f32x4 o[2][4];
  float m_run[2][4], l_run[2][4];
  #pragma unroll
  for (int m = 0; m < 2; ++m)
    #pragma unroll
    for (int r = 0; r < 4; ++r) { m_run[m][r] = -1e30f; l_run[m][r] = 0.f; }
  #pragma unroll
  for (int m = 0; m < 2; ++m)
    #pragma unroll
    for (int nn = 0; nn < 4; ++nn)
      o[m][nn] = (f32x4){0.f, 0.f, 0.f, 0.f};

  const bf16* kb = qkv + (size_t)(b * 1024) * 3072 + 1024 + h * 64;
  const bf16* vb = vT + (size_t)(bh * 64) * 1024;
  const int* tb = tokens + b * 1024;

  for (int jt = 0; jt <= qt; ++jt) {
    const int j0 = jt * 128;
    __syncthreads();  // previous iteration's LDS reads complete
    #pragma unroll
    for (int i = 0; i < 4; ++i)
      gload16(kb + (size_t)(j0 + i * 32 + (t >> 3)) * 3072 + (t & 7) * 8,
              Ks + i * 2048 + w * 512);
    #pragma unroll
    for (int i = 0; i < 4; ++i)
      gload16(vb + (size_t)(i * 16 + (t >> 4)) * 1024 + j0 + (t & 15) * 8,
              VTs + i * 2048 + w * 512);
    __syncthreads();  // staged tiles visible

    // S = Q K^T for this wave's 32 rows x 128 cols
    f32x4 s[2][8];
    #pragma unroll
    for (int m = 0; m < 2; ++m)
      #pragma unroll
      for (int n = 0; n < 8; ++n)
        s[m][n] = (f32x4){0.f, 0.f, 0.f, 0.f};
    #pragma unroll
    for (int ks = 0; ks < 2; ++ks) {
      #pragma unroll
      for (int n = 0; n < 8; ++n) {
        const bf16x8 bk = *(const bf16x8*)&Ks[(n * 16 + l15) * 64 + ks * 32 + l4 * 8];
        #pragma unroll
        for (int m = 0; m < 2; ++m)
          s[m][n] = mfma16(aq[m][ks], bk, s[m][n]);
      }
    }

    // per-lane pad flags for its 8 key columns
    float padv[8];
    #pragma unroll
    for (int n = 0; n < 8; ++n)
      padv[n] = (tb[j0 + n * 16 + l15] == 0) ? 1.f : 0.f;

    // online softmax per q-row; write P to LDS
    #pragma unroll
    for (int m = 0; m < 2; ++m) {
      #pragma unroll
      for (int r = 0; r < 4; ++r) {
        const int qrow = q0 + w * 32 + m * 16 + l4 * 4 + r;
        float vals[8];
        float mx = -1e30f;
        #pragma unroll
        for (int n = 0; n < 8; ++n) {
          const int jg = j0 + n * 16 + l15;
          float v = s[m][n][r] * 0.125f;
          if (jg > qrow || padv[n] != 0.f) v = -1e9f;
          vals[n] = v;
          mx = fmaxf(mx, v);
        }
        #pragma unroll
        for (int d = 1; d < 16; d <<= 1) mx = fmaxf(mx, __shfl_xor(mx, d));
        const float newm = fmaxf(m_run[m][r], mx);
        const float sc = __expf(m_run[m][r] - newm);
        m_run[m][r] = newm;
        float rs = 0.f;
        #pragma unroll
        for (int n = 0; n < 8; ++n) {
          const float pv = __expf(vals[n] - newm);
          vals[n] = pv;
          rs += pv;
        }
        #pragma unroll
        for (int d = 1; d < 16; d <<= 1) rs += __shfl_xor(rs, d);
        l_run[m][r] = l_run[m][r] * sc + rs;
        #pragma unroll
        for (int nn = 0; nn < 4; ++nn) o[m][nn][r] = o[m][nn][r] * sc;
        #pragma unroll
        for (int n = 0; n < 8; ++n)
          Ps[(w * 32 + m * 16 + l4 * 4 + r) * 128 + n * 16 + l15] = f2b(vals[n]);
      }
    }
    __syncthreads();  // P visible

    // O += P V
    #pragma unroll
    for (int ks = 0; ks < 4; ++ks) {
      bf16x8 ap[2];
      #pragma unroll
      for (int m = 0; m < 2; ++m)
        ap[m] = *(const bf16x8*)&Ps[(w * 32 + m * 16 + l15) * 128 + ks * 32 + l4 * 8];
      #pragma unroll
      for (int nn = 0; nn < 4; ++nn) {
        const bf16x8 bv = *(const bf16x8*)&VTs[(nn * 16 + l15) * 128 + ks * 32 + l4 * 8];
        #pragma unroll
        for (int m = 0; m < 2; ++m)
          o[m][nn] = mfma16(ap[m], bv, o[m][nn]);
      }
    }
  }

  // epilogue: ctx = O / l
  #pragma unroll
  for (int m = 0; m < 2; ++m) {
    #pragma unroll
    for (int r = 0; r < 4; ++r) {
      const float inv = 1.0f / l_run[m][r];
      const int qrow = q0 + w * 32 + m * 16 + l4 * 4 + r;
      #pragma unroll
      for (int nn = 0; nn < 4; ++nn)
        ctx[(size_t)(b * 1024 + qrow) * 1024 + h * 64 + nn * 16 + l15] =
            f2b(o[m][nn][r] * inv);
    }
  }
}

// ------------- fixup for all-masked rows (leading pad tokens) -------------
// reference: softmax of all -1e9 row = uniform over ALL S -> ctx = mean(v)
__global__ __launch_bounds__(64) void attn_fixup_kernel(
    const int* __restrict__ tokens, const bf16* __restrict__ vT,
    bf16* __restrict__ ctx)
{
  const int bh = blockIdx.x;
  const int b = bh >> 4, h = bh & 15;
  __shared__ int p0s;
  if (threadIdx.x == 0) {
    int p = 0;
    const int* tb = tokens + b * 1024;
    while (p < 1024 && tb[p] == 0) ++p;
    p0s = p;
  }
  __syncthreads();
  const int P0 = p0s;
  if (P0 == 0) return;
  const int dk = threadIdx.x;
  const bf16* vrow = vT + (size_t)(bh * 64 + dk) * 1024;
  float sum = 0.f;
  for (int sIdx = 0; sIdx < 1024; ++sIdx) sum += b2f(vrow[sIdx]);
  const bf16 mv = f2b(sum * (1.0f / 1024.0f));
  for (int q = 0; q < P0; ++q)
    ctx[(size_t)(b * 1024 + q) * 1024 + h * 64 + dk] = mv;
}

// ---------------- host ----------------
extern "C" void kernel_launch(void* const* d_in, const int* in_sizes, int n_in,
                              void* d_out, int out_size, void* d_ws, size_t ws_size,
                              hipStream_t stream)
{
  (void)in_sizes; (void)n_in; (void)out_size; (void)ws_size;
  const int*   tokens = (const int*)d_in[0];
  const float* emb  = (const float*)d_in[1];
  const float* pe   = (const float*)d_in[2];
  const float* Wq   = (const float*)d_in[3];
  const float* Wk   = (const float*)d_in[4];
  const float* Wv   = (const float*)d_in[5];
  const float* Wo   = (const float*)d_in[6];
  const float* bo   = (const float*)d_in[7];
  const float* g1   = (const float*)d_in[8];
  const float* be1  = (const float*)d_in[9];
  const float* g2   = (const float*)d_in[10];
  const float* be2  = (const float*)d_in[11];
  const float* W1   = (const float*)d_in[12];
  const float* b1   = (const float*)d_in[13];
  const float* W2   = (const float*)d_in[14];
  const float* b2   = (const float*)d_in[15];
  const float* gf   = (const float*)d_in[16];
  const float* bff  = (const float*)d_in[17];
  const float* Wout = (const float*)d_in[18];
  const float* bout = (const float*)d_in[19];
  float* out = (float*)d_out;

  char* p = (char*)d_ws;
  auto alloc = [&](size_t bytes) {
    char* q = p;
    p += (bytes + 255) & ~(size_t)255;
    return q;
  };
  float* x    = (float*)alloc((size_t)2048 * 1024 * 4);
  bf16* h     = (bf16*)alloc((size_t)2048 * 1024 * 2);
  bf16* qkv   = (bf16*)alloc((size_t)2048 * 3072 * 2);
  bf16* vT    = (bf16*)alloc((size_t)2048 * 1024 * 2);
  bf16* ctx   = (bf16*)alloc((size_t)2048 * 1024 * 2);
  bf16* ff    = (bf16*)alloc((size_t)2048 * 4096 * 2);
  bf16* WqkvT = (bf16*)alloc((size_t)3072 * 1024 * 2);
  bf16* WoT   = (bf16*)alloc((size_t)1024 * 1024 * 2);
  bf16* W1T   = (bf16*)alloc((size_t)4096 * 1024 * 2);
  bf16* W2T   = (bf16*)alloc((size_t)1024 * 4096 * 2);
  bf16* WoutT = (bf16*)alloc((size_t)32000 * 1024 * 2);

  const size_t DD = (size_t)1024 * 1024;
  const size_t DF = (size_t)1024 * 4096;

  embed_kernel<<<2048, 256, 0, stream>>>(tokens, emb, pe, x);

  for (int l = 0; l < 6; ++l) {
    transpose_cast_kernel<<<dim3(16, 16), 256, 0, stream>>>(Wq + l * DD, WqkvT, 1024, 1024);
    transpose_cast_kernel<<<dim3(16, 16), 256, 0, stream>>>(Wk + l * DD, WqkvT + 1024 * 1024, 1024, 1024);
    transpose_cast_kernel<<<dim3(16, 16), 256, 0, stream>>>(Wv + l * DD, WqkvT + 2048 * 1024, 1024, 1024);
    transpose_cast_kernel<<<dim3(16, 16), 256, 0, stream>>>(Wo + l * DD, WoT, 1024, 1024);
    transpose_cast_kernel<<<dim3(64, 16), 256, 0, stream>>>(W1 + l * DF, W1T, 4096, 1024);
    transpose_cast_kernel<<<dim3(16, 64), 256, 0, stream>>>(W2 + l * DF, W2T, 1024, 4096);

    ln_kernel<<<2048, 256, 0, stream>>>(x, g1 + l * 1024, be1 + l * 1024, h);
    gemm_bt<0><<<16 * 24, 256, 0, stream>>>(h, 1024, WqkvT, 1024, qkv, 3072,
                                            (const float*)nullptr, 1024, 24);
    transpose_v_kernel<<<dim3(16, 32), 256, 0, stream>>>(qkv, vT);
    attn_kernel<<<dim3(8, 32), 256, 0, stream>>>(qkv, vT, tokens, ctx);
    attn_fixup_kernel<<<32, 64, 0, stream>>>(tokens, vT, ctx);
    gemm_bt<3><<<16 * 8, 256, 0, stream>>>(ctx, 1024, WoT, 1024, x, 1024,
                                           bo + l * 1024, 1024, 8);
    ln_kernel<<<2048, 256, 0, stream>>>(x, g2 + l * 1024, be2 + l * 1024, h);
    gemm_bt<2><<<16 * 32, 256, 0, stream>>>(h, 1024, W1T, 1024, ff, 4096,
                                            b1 + l * 4096, 1024, 32);
    gemm_bt<3><<<16 * 8, 256, 0, stream>>>(ff, 4096, W2T, 4096, x, 1024,
                                           b2 + l * 1024, 4096, 8);
  }

  ln_kernel<<<2048, 256, 0, stream>>>(x, gf, bff, h);
  transpose_cast_kernel<<<dim3(500, 16), 256, 0, stream>>>(Wout, WoutT, 32000, 1024);
  gemm_bt<1><<<16 * 250, 256, 0, stream>>>(h, 1024, WoutT, 1024, out, 32000,
                                           bout, 1024, 250);
}

// Round 3
// 1577.571 us; speedup vs baseline: 1.3180x; 1.3180x over previous
//
#include <hip/hip_runtime.h>
#include <hip/hip_bf16.h>
#include <stdint.h>

typedef __hip_bfloat16 bf16;
typedef __attribute__((ext_vector_type(8))) short bf16x8;
typedef __attribute__((ext_vector_type(4))) float f32x4;

#define DEV static __device__ __forceinline__

DEV float b2f(bf16 v) { return __bfloat162float(v); }
DEV bf16  f2b(float v) { return __float2bfloat16(v); }

DEV void gload16(const void* g, void* l) {
  __builtin_amdgcn_global_load_lds(
      (__attribute__((address_space(1))) void*)(void*)g,
      (__attribute__((address_space(3))) void*)l, 16, 0, 0);
}

DEV f32x4 mfma16(bf16x8 a, bf16x8 b, f32x4 c) {
  return __builtin_amdgcn_mfma_f32_16x16x32_bf16(a, b, c, 0, 0, 0);
}

// ---------------- embed: x = emb[tok]*32 + pe (all f32) ----------------
__global__ __launch_bounds__(256) void embed_kernel(
    const int* __restrict__ tok, const float* __restrict__ emb,
    const float* __restrict__ pe, float* __restrict__ x)
{
  const int r = blockIdx.x, t = threadIdx.x;
  const int s = r & 1023;
  const int tk = tok[r];
  const int d = t * 4;
  const float* ep = emb + (size_t)tk * 1024 + d;
  const float* pp = pe + (size_t)s * 1024 + d;
  float* xp = x + (size_t)r * 1024 + d;
  #pragma unroll
  for (int j = 0; j < 4; ++j)
    xp[j] = ep[j] * 32.0f + pp[j];
}

// ---------------- layernorm: h = LN(x)*g + b (f32 in, bf16 out) ----------------
__global__ __launch_bounds__(256) void ln_kernel(
    const float* __restrict__ x, const float* __restrict__ g,
    const float* __restrict__ be, bf16* __restrict__ h)
{
  const int r = blockIdx.x, t = threadIdx.x;
  const float4 v = ((const float4*)(x + (size_t)r * 1024))[t];
  float s  = v.x + v.y + v.z + v.w;
  float sq = v.x * v.x + v.y * v.y + v.z * v.z + v.w * v.w;
  #pragma unroll
  for (int d = 1; d < 64; d <<= 1) {
    s  += __shfl_xor(s, d);
    sq += __shfl_xor(sq, d);
  }
  __shared__ float red[8];
  const int w = t >> 6, l = t & 63;
  if (l == 0) { red[w] = s; red[4 + w] = sq; }
  __syncthreads();
  s  = red[0] + red[1] + red[2] + red[3];
  sq = red[4] + red[5] + red[6] + red[7];
  const float mean = s * (1.0f / 1024.0f);
  const float var  = sq * (1.0f / 1024.0f) - mean * mean;
  const float inv  = 1.0f / sqrtf(var + 1e-5f);
  bf16* hp = h + (size_t)r * 1024 + t * 4;
  const float* gp = g + t * 4;
  const float* bp = be + t * 4;
  const float vv[4] = {v.x, v.y, v.z, v.w};
  #pragma unroll
  for (int j = 0; j < 4; ++j)
    hp[j] = f2b((vv[j] - mean) * inv * gp[j] + bp[j]);
}

// ------------- 64x64 transpose+cast tile body -------------
DEV void transpose_tile(const float* __restrict__ in, bf16* __restrict__ out,
                        int ldin, int ldout, int r0, int c0, int t)
{
  __shared__ bf16 tile[64][64];
  #pragma unroll
  for (int i = 0; i < 4; ++i) {
    const int r = i * 16 + (t >> 4), c = (t & 15) * 4;
    const float4 v = *(const float4*)&in[(size_t)(r0 + r) * ldin + c0 + c];
    tile[r][c + 0] = f2b(v.x);
    tile[r][c + 1] = f2b(v.y);
    tile[r][c + 2] = f2b(v.z);
    tile[r][c + 3] = f2b(v.w);
  }
  __syncthreads();
  #pragma unroll
  for (int i = 0; i < 2; ++i) {
    const int oc = i * 32 + (t >> 3);
    const int rr = (t & 7) * 8;
    unsigned short tmp[8] __attribute__((aligned(16)));
    #pragma unroll
    for (int j = 0; j < 8; ++j)
      tmp[j] = ((const unsigned short*)tile)[(rr + j) * 64 + oc];
    *(uint4*)&out[(size_t)(c0 + oc) * ldout + r0 + rr] = *(const uint4*)tmp;
  }
}

// generic single-matrix transpose+cast (used for Wout)
__global__ __launch_bounds__(256) void transpose_cast_kernel(
    const float* __restrict__ in, bf16* __restrict__ out, int ldin, int ldout)
{
  transpose_tile(in, out, ldin, ldout, blockIdx.y * 64, blockIdx.x * 64, threadIdx.x);
}

// per-layer fused weight prep: 3072 tiles (Wq,Wk,Wv,Wo: 256 each; W1,W2: 1024 each)
__global__ __launch_bounds__(256) void prep_layer_kernel(
    const float* __restrict__ Wq, const float* __restrict__ Wk,
    const float* __restrict__ Wv, const float* __restrict__ Wo,
    const float* __restrict__ W1, const float* __restrict__ W2,
    bf16* __restrict__ WqkvT, bf16* __restrict__ WoT,
    bf16* __restrict__ W1T, bf16* __restrict__ W2T)
{
  const int wid = blockIdx.x;
  const float* src; bf16* dst; int ldin, ldout, tx, ty;
  if (wid < 768) {
    const int m = wid >> 8, tt = wid & 255;
    src = (m == 0) ? Wq : (m == 1) ? Wk : Wv;
    dst = WqkvT + (size_t)m * 1024 * 1024;
    ldin = 1024; ldout = 1024; tx = tt & 15; ty = tt >> 4;
  } else if (wid < 1024) {
    const int tt = wid - 768;
    src = Wo; dst = WoT; ldin = 1024; ldout = 1024; tx = tt & 15; ty = tt >> 4;
  } else if (wid < 2048) {
    const int tt = wid - 1024;
    src = W1; dst = W1T; ldin = 4096; ldout = 1024; tx = tt & 63; ty = tt >> 6;
  } else {
    const int tt = wid - 2048;
    src = W2; dst = W2T; ldin = 1024; ldout = 4096; tx = tt & 15; ty = tt >> 4;
  }
  transpose_tile(src, dst, ldin, ldout, ty * 64, tx * 64, threadIdx.x);
}

// ---- v transpose (bf16->bf16): vT[bh][dk][s] = qkv[b*S+s][2048+h*64+dk] ----
// grid: (S/64, B*H), block 256
__global__ __launch_bounds__(256) void transpose_v_kernel(
    const bf16* __restrict__ qkv, bf16* __restrict__ vT)
{
  __shared__ bf16 tile[64][64];
  const int t = threadIdx.x;
  const int s0 = blockIdx.x * 64;
  const int bh = blockIdx.y;
  const int b = bh >> 4, h = bh & 15;
  const bf16* in = qkv + (size_t)(b * 1024) * 3072 + 2048 + h * 64;
  #pragma unroll
  for (int i = 0; i < 2; ++i) {
    const int r = i * 32 + (t >> 3), c = (t & 7) * 8;
    *(uint4*)&tile[r][c] = *(const uint4*)&in[(size_t)(s0 + r) * 3072 + c];
  }
  __syncthreads();
  bf16* out = vT + (size_t)(bh * 64) * 1024;
  #pragma unroll
  for (int i = 0; i < 2; ++i) {
    const int oc = i * 32 + (t >> 3);   // dk
    const int rr = (t & 7) * 8;         // s offset
    unsigned short tmp[8] __attribute__((aligned(16)));
    #pragma unroll
    for (int j = 0; j < 8; ++j)
      tmp[j] = ((const unsigned short*)tile)[(rr + j) * 64 + oc];
    *(uint4*)&out[(size_t)oc * 1024 + s0 + rr] = *(const uint4*)tmp;
  }
}

// ---------------- GEMM: C(MxN) = A(MxK,row) * BT(NxK,row)^T (+epilogue) ------
// EPI: 0 = bf16 store; 1 = +bias f32 store (logits); 2 = gelu(acc+bias) bf16;
//      3 = f32 residual: atomicAdd X += acc (+bias on slice z==0)
// grid: (M/BM, N/128, KSLICES), block 256 (4 waves), K-slice length ksl
template<int EPI, int BM>
__global__ __launch_bounds__(256) void gemm_bt(
    const bf16* __restrict__ A, int lda,
    const bf16* __restrict__ BT, int ldb,
    void* __restrict__ Cp, int ldc,
    const float* __restrict__ bias,
    int ksl)
{
  __shared__ bf16 As[BM * 32];
  __shared__ bf16 Bs[128 * 32];
  constexpr int MR = BM / 32;           // m-fragment repeats per wave
  const int t = threadIdx.x;
  const int bm = blockIdx.x, bn = blockIdx.y;
  const int w = t >> 6, l = t & 63;
  const int wr = (w >> 1) * (BM / 2), wc = (w & 1) * 64;
  const int l15 = l & 15, l4 = l >> 4;

  const bf16* gA = A  + (size_t)(bm * BM  + (t >> 2)) * lda + (t & 3) * 8;
  const bf16* gB = BT + (size_t)(bn * 128 + (t >> 2)) * ldb + (t & 3) * 8;
  bf16* lA = As + w * 512;
  bf16* lB = Bs + w * 512;

  f32x4 acc[MR][4];
  #pragma unroll
  for (int m = 0; m < MR; ++m)
    #pragma unroll
    for (int n = 0; n < 4; ++n)
      acc[m][n] = (f32x4){0.f, 0.f, 0.f, 0.f};

  const int kbeg = blockIdx.z * ksl;
  for (int k0 = kbeg; k0 < kbeg + ksl; k0 += 32) {
    gload16(gA + k0, lA);
    if constexpr (BM == 128) gload16(gA + (size_t)64 * lda + k0, lA + 2048);
    gload16(gB + k0, lB);
    gload16(gB + (size_t)64 * ldb + k0, lB + 2048);
    __syncthreads();
    bf16x8 af[MR], bfr[4];
    #pragma unroll
    for (int m = 0; m < MR; ++m)
      af[m] = *(const bf16x8*)&As[(wr + m * 16 + l15) * 32 + l4 * 8];
    #pragma unroll
    for (int n = 0; n < 4; ++n)
      bfr[n] = *(const bf16x8*)&Bs[(wc + n * 16 + l15) * 32 + l4 * 8];
    #pragma unroll
    for (int m = 0; m < MR; ++m)
      #pragma unroll
      for (int n = 0; n < 4; ++n)
        acc[m][n] = mfma16(af[m], bfr[n], acc[m][n]);
    __syncthreads();
  }

  const int crow = bm * BM + wr, ccol = bn * 128 + wc;
  #pragma unroll
  for (int n = 0; n < 4; ++n) {
    const int col = ccol + n * 16 + l15;
    float bv = 0.f;
    if (EPI == 1 || EPI == 2) bv = bias[col];
    if (EPI == 3 && blockIdx.z == 0) bv = bias[col];
    #pragma unroll
    for (int m = 0; m < MR; ++m) {
      const int row = crow + m * 16 + l4 * 4;
      #pragma unroll
      for (int r = 0; r < 4; ++r) {
        const float v = acc[m][n][r];
        if (EPI == 0) {
          ((bf16*)Cp)[(size_t)(row + r) * ldc + col] = f2b(v);
        } else if (EPI == 1) {
          ((float*)Cp)[(size_t)(row + r) * ldc + col] = v + bv;
        } else if (EPI == 2) {
          const float u = v + bv;
          const float gel = 0.5f * u * (1.0f + erff(u * 0.70710678118654752f));
          ((bf16*)Cp)[(size_t)(row + r) * ldc + col] = f2b(gel);
        } else {
          atomicAdd(&((float*)Cp)[(size_t)(row + r) * ldc + col], v + bv);
        }
      }
    }
  }
}

// ---------------- flash attention (LDS XOR-swizzled) ----------------
// grid: (S/128, B*H), block 256 (4 waves; wave w owns q-rows w*32..w*32+31)
// LDS layouts: Ks[key][c ^ ((key&7)*8)], VTs[dk][c ^ ((dk&15)*8)],
//              Ps[row][c ^ ((row&15)*8)]  (elem-index XOR, multiples of 8)
__global__ __launch_bounds__(256) void attn_kernel(
    const bf16* __restrict__ qkv, const bf16* __restrict__ vT,
    const int* __restrict__ tokens, bf16* __restrict__ ctx)
{
  __shared__ bf16 Ks[128 * 64];
  __shared__ bf16 VTs[64 * 128];
  __shared__ bf16 Ps[128 * 128];

  const int qt = blockIdx.x;
  const int bh = blockIdx.y;
  const int b = bh >> 4, h = bh & 15;
  const int t = threadIdx.x, w = t >> 6, l = t & 63;
  const int l15 = l & 15, l4 = l >> 4;
  const int q0 = qt * 128;

  // Q fragments in registers (each wave its own 32 rows)
  bf16x8 aq[2][2];
  #pragma unroll
  for (int m = 0; m < 2; ++m)
    #pragma unroll
    for (int ks = 0; ks < 2; ++ks)
      aq[m][ks] = *(const bf16x8*)(qkv +
          (size_t)(b * 1024 + q0 + w * 32 + m * 16 + l15) * 3072 +
          h * 64 + ks * 32 + l4 * 8);

  f32x4 o[2][4];
  float m_run[2][4], l_run[2][4];
  #pragma unroll
  for (int m = 0; m < 2; ++m)
    #pragma unroll
    for (int r = 0; r < 4; ++r) { m_run[m][r] = -1e30f; l_run[m][r] = 0.f; }
  #pragma unroll
  for (int m = 0; m < 2; ++m)
    #pragma unroll
    for (int nn = 0; nn < 4; ++nn)
      o[m][nn] = (f32x4){0.f, 0.f, 0.f, 0.f};

  const bf16* kb = qkv + (size_t)(b * 1024) * 3072 + 1024 + h * 64;
  const bf16* vb = vT + (size_t)(bh * 64) * 1024;
  const int* tb = tokens + b * 1024;

  // staging swizzle offsets (pre-swizzled GLOBAL source, linear LDS dest)
  const int kSrcCol = ((t & 7) ^ ((t >> 3) & 7)) * 8;   // K: row&7 = (t>>3)&7
  const int vSrcCol = ((t & 15) ^ (t >> 4)) * 8;        // V: row&15 = t>>4

  for (int jt = 0; jt <= qt; ++jt) {
    const int j0 = jt * 128;
    __syncthreads();  // previous iteration's LDS reads complete
    #pragma unroll
    for (int i = 0; i < 4; ++i)
      gload16(kb + (size_t)(j0 + i * 32 + (t >> 3)) * 3072 + kSrcCol,
              Ks + i * 2048 + w * 512);
    #pragma unroll
    for (int i = 0; i < 4; ++i)
      gload16(vb + (size_t)(i * 16 + (t >> 4)) * 1024 + j0 + vSrcCol,
              VTs + i * 2048 + w * 512);
    __syncthreads();  // staged tiles visible

    // S = Q K^T for this wave's 32 rows x 128 cols
    f32x4 s[2][8];
    #pragma unroll
    for (int m = 0; m < 2; ++m)
      #pragma unroll
      for (int n = 0; n < 8; ++n)
        s[m][n] = (f32x4){0.f, 0.f, 0.f, 0.f};
    #pragma unroll
    for (int ks = 0; ks < 2; ++ks) {
      #pragma unroll
      for (int n = 0; n < 8; ++n) {
        const bf16x8 bk = *(const bf16x8*)
            &Ks[(n * 16 + l15) * 64 + ((ks * 32 + l4 * 8) ^ ((l15 & 7) * 8))];
        #pragma unroll
        for (int m = 0; m < 2; ++m)
          s[m][n] = mfma16(aq[m][ks], bk, s[m][n]);
      }
    }

    // per-lane pad flags for its 8 key columns
    float padv[8];
    #pragma unroll
    for (int n = 0; n < 8; ++n)
      padv[n] = (tb[j0 + n * 16 + l15] == 0) ? 1.f : 0.f;

    // online softmax per q-row; write P to LDS (swizzled)
    #pragma unroll
    for (int m = 0; m < 2; ++m) {
      #pragma unroll
      for (int r = 0; r < 4; ++r) {
        const int rloc = l4 * 4 + r;                      // row&15 at write
        const int qrow = q0 + w * 32 + m * 16 + rloc;
        float vals[8];
        float mx = -1e30f;
        #pragma unroll
        for (int n = 0; n < 8; ++n) {
          const int jg = j0 + n * 16 + l15;
          float v = s[m][n][r] * 0.125f;
          if (jg > qrow || padv[n] != 0.f) v = -1e9f;
          vals[n] = v;
          mx = fmaxf(mx, v);
        }
        #pragma unroll
        for (int d = 1; d < 16; d <<= 1) mx = fmaxf(mx, __shfl_xor(mx, d));
        const float newm = fmaxf(m_run[m][r], mx);
        const float sc = __expf(m_run[m][r] - newm);
        m_run[m][r] = newm;
        float rs = 0.f;
        #pragma unroll
        for (int n = 0; n < 8; ++n) {
          const float pv = __expf(vals[n] - newm);
          vals[n] = pv;
          rs += pv;
        }
        #pragma unroll
        for (int d = 1; d < 16; d <<= 1) rs += __shfl_xor(rs, d);
        l_run[m][r] = l_run[m][r] * sc + rs;
        #pragma unroll
        for (int nn = 0; nn < 4; ++nn) o[m][nn][r] = o[m][nn][r] * sc;
        #pragma unroll
        for (int n = 0; n < 8; ++n)
          Ps[(w * 32 + m * 16 + rloc) * 128 +
             ((n * 16 + l15) ^ (rloc * 8))] = f2b(vals[n]);
      }
    }
    __syncthreads();  // P visible

    // O += P V
    #pragma unroll
    for (int ks = 0; ks < 4; ++ks) {
      bf16x8 ap[2];
      #pragma unroll
      for (int m = 0; m < 2; ++m)
        ap[m] = *(const bf16x8*)
            &Ps[(w * 32 + m * 16 + l15) * 128 + ((ks * 32 + l4 * 8) ^ (l15 * 8))];
      #pragma unroll
      for (int nn = 0; nn < 4; ++nn) {
        const bf16x8 bv = *(const bf16x8*)
            &VTs[(nn * 16 + l15) * 128 + ((ks * 32 + l4 * 8) ^ (l15 * 8))];
        #pragma unroll
        for (int m = 0; m < 2; ++m)
          o[m][nn] = mfma16(ap[m], bv, o[m][nn]);
      }
    }
  }

  // epilogue: ctx = O / l
  #pragma unroll
  for (int m = 0; m < 2; ++m) {
    #pragma unroll
    for (int r = 0; r < 4; ++r) {
      const float inv = 1.0f / l_run[m][r];
      const int qrow = q0 + w * 32 + m * 16 + l4 * 4 + r;
      #pragma unroll
      for (int nn = 0; nn < 4; ++nn)
        ctx[(size_t)(b * 1024 + qrow) * 1024 + h * 64 + nn * 16 + l15] =
            f2b(o[m][nn][r] * inv);
    }
  }
}

// ------------- fixup for all-masked rows (leading pad tokens) -------------
__global__ __launch_bounds__(64) void attn_fixup_kernel(
    const int* __restrict__ tokens, const bf16* __restrict__ vT,
    bf16* __restrict__ ctx)
{
  const int bh = blockIdx.x;
  const int b = bh >> 4, h = bh & 15;
  __shared__ int p0s;
  if (threadIdx.x == 0) {
    int p = 0;
    const int* tb = tokens + b * 1024;
    while (p < 1024 && tb[p] == 0) ++p;
    p0s = p;
  }
  __syncthreads();
  const int P0 = p0s;
  if (P0 == 0) return;
  const int dk = threadIdx.x;
  const bf16* vrow = vT + (size_t)(bh * 64 + dk) * 1024;
  float sum = 0.f;
  for (int sIdx = 0; sIdx < 1024; ++sIdx) sum += b2f(vrow[sIdx]);
  const bf16 mv = f2b(sum * (1.0f / 1024.0f));
  for (int q = 0; q < P0; ++q)
    ctx[(size_t)(b * 1024 + q) * 1024 + h * 64 + dk] = mv;
}

// ---------------- host ----------------
extern "C" void kernel_launch(void* const* d_in, const int* in_sizes, int n_in,
                              void* d_out, int out_size, void* d_ws, size_t ws_size,
                              hipStream_t stream)
{
  (void)in_sizes; (void)n_in; (void)out_size; (void)ws_size;
  const int*   tokens = (const int*)d_in[0];
  const float* emb  = (const float*)d_in[1];
  const float* pe   = (const float*)d_in[2];
  const float* Wq   = (const float*)d_in[3];
  const float* Wk   = (const float*)d_in[4];
  const float* Wv   = (const float*)d_in[5];
  const float* Wo   = (const float*)d_in[6];
  const float* bo   = (const float*)d_in[7];
  const float* g1   = (const float*)d_in[8];
  const float* be1  = (const float*)d_in[9];
  const float* g2   = (const float*)d_in[10];
  const float* be2  = (const float*)d_in[11];
  const float* W1   = (const float*)d_in[12];
  const float* b1   = (const float*)d_in[13];
  const float* W2   = (const float*)d_in[14];
  const float* b2   = (const float*)d_in[15];
  const float* gf   = (const float*)d_in[16];
  const float* bff  = (const float*)d_in[17];
  const float* Wout = (const float*)d_in[18];
  const float* bout = (const float*)d_in[19];
  float* out = (float*)d_out;

  char* p = (char*)d_ws;
  auto alloc = [&](size_t bytes) {
    char* q = p;
    p += (bytes + 255) & ~(size_t)255;
    return q;
  };
  float* x    = (float*)alloc((size_t)2048 * 1024 * 4);
  bf16* h     = (bf16*)alloc((size_t)2048 * 1024 * 2);
  bf16* qkv   = (bf16*)alloc((size_t)2048 * 3072 * 2);
  bf16* vT    = (bf16*)alloc((size_t)2048 * 1024 * 2);
  bf16* ctx   = (bf16*)alloc((size_t)2048 * 1024 * 2);
  bf16* ff    = (bf16*)alloc((size_t)2048 * 4096 * 2);
  bf16* WqkvT = (bf16*)alloc((size_t)3072 * 1024 * 2);
  bf16* WoT   = (bf16*)alloc((size_t)1024 * 1024 * 2);
  bf16* W1T   = (bf16*)alloc((size_t)4096 * 1024 * 2);
  bf16* W2T   = (bf16*)alloc((size_t)1024 * 4096 * 2);
  bf16* WoutT = (bf16*)alloc((size_t)32000 * 1024 * 2);

  const size_t DD = (size_t)1024 * 1024;
  const size_t DF = (size_t)1024 * 4096;

  embed_kernel<<<2048, 256, 0, stream>>>(tokens, emb, pe, x);

  for (int l = 0; l < 6; ++l) {
    prep_layer_kernel<<<3072, 256, 0, stream>>>(
        Wq + l * DD, Wk + l * DD, Wv + l * DD, Wo + l * DD,
        W1 + l * DF, W2 + l * DF, WqkvT, WoT, W1T, W2T);

    ln_kernel<<<2048, 256, 0, stream>>>(x, g1 + l * 1024, be1 + l * 1024, h);
    // QKV: M=2048 N=3072 K=1024, BM=64 -> 768 blocks (3/CU)
    gemm_bt<0, 64><<<dim3(32, 24, 1), 256, 0, stream>>>(
        h, 1024, WqkvT, 1024, qkv, 3072, (const float*)nullptr, 1024);
    transpose_v_kernel<<<dim3(16, 32), 256, 0, stream>>>(qkv, vT);
    attn_kernel<<<dim3(8, 32), 256, 0, stream>>>(qkv, vT, tokens, ctx);
    attn_fixup_kernel<<<32, 64, 0, stream>>>(tokens, vT, ctx);
    // Wo: M=2048 N=1024 K=1024, BM=64 + splitK2 -> 512 blocks (2/CU)
    gemm_bt<3, 64><<<dim3(32, 8, 2), 256, 0, stream>>>(
        ctx, 1024, WoT, 1024, x, 1024, bo + l * 1024, 512);
    ln_kernel<<<2048, 256, 0, stream>>>(x, g2 + l * 1024, be2 + l * 1024, h);
    // FFN1: M=2048 N=4096 K=1024, BM=128 -> 512 blocks (2/CU)
    gemm_bt<2, 128><<<dim3(16, 32, 1), 256, 0, stream>>>(
        h, 1024, W1T, 1024, ff, 4096, b1 + l * 4096, 1024);
    // FFN2: M=2048 N=1024 K=4096, BM=128 + splitK4 -> 512 blocks (2/CU)
    gemm_bt<3, 128><<<dim3(16, 8, 4), 256, 0, stream>>>(
        ff, 4096, W2T, 4096, x, 1024, b2 + l * 1024, 1024);
  }

  ln_kernel<<<2048, 256, 0, stream>>>(x, gf, bff, h);
  transpose_cast_kernel<<<dim3(500, 16), 256, 0, stream>>>(Wout, WoutT, 32000, 1024);
  // logits: M=2048 N=32000 K=1024, BM=128 -> 4000 blocks
  gemm_bt<1, 128><<<dim3(16, 250, 1), 256, 0, stream>>>(
      h, 1024, WoutT, 1024, out, 32000, bout, 1024);
}